// Round 4
// baseline (793.770 us; speedup 1.0000x reference)
//
#include <hip/hip_runtime.h>
#include <hip/hip_fp16.h>

typedef _Float16 half_t;
typedef _Float16 f16x8 __attribute__((ext_vector_type(8)));
typedef _Float16 f16x4 __attribute__((ext_vector_type(4)));
typedef float f32x4 __attribute__((ext_vector_type(4)));

#define SEQ 4096
#define DDIM 1024
#define NBATCH 4

__device__ __forceinline__ void gload16(const half_t* g, half_t* l) {
  __builtin_amdgcn_global_load_lds((const __attribute__((address_space(1))) void*)g,
                                   (__attribute__((address_space(3))) void*)l, 16, 0, 0);
}

// ---------------- fp32 -> fp16 elementwise convert ----------------
__global__ __launch_bounds__(256) void conv_f16(const float* __restrict__ src,
                                                half_t* __restrict__ dst) {
  int i = blockIdx.x * 256 + threadIdx.x;
  float4 x = ((const float4*)src)[i];
  f16x4 o = {(half_t)x.x, (half_t)x.y, (half_t)x.z, (half_t)x.w};
  *(f16x4*)(dst + (size_t)i * 4) = o;
}

// ---------------- enc [b][e][d] fp32 -> encT [b][d][e] fp16 ----------------
__global__ __launch_bounds__(256) void transpose_f16(const float* __restrict__ src,
                                                     half_t* __restrict__ dst) {
  __shared__ float tile[32][33];
  int b = blockIdx.z;
  int e0 = blockIdx.x * 32, d0 = blockIdx.y * 32;
  const float* s = src + (size_t)b * SEQ * DDIM;
  half_t* dt = dst + (size_t)b * DDIM * SEQ;
  int tx = threadIdx.x & 31, ty = threadIdx.x >> 5;
#pragma unroll
  for (int i = 0; i < 4; i++) {
    int e = e0 + ty + i * 8;
    tile[ty + i * 8][tx] = s[(size_t)e * DDIM + d0 + tx];
  }
  __syncthreads();
#pragma unroll
  for (int i = 0; i < 4; i++) {
    int d = d0 + ty + i * 8;
    dt[(size_t)d * SEQ + e0 + tx] = (half_t)tile[tx][ty + i * 8];
  }
}

// ---------------- fp16 BT GEMM (batched): C[z][M][N] = A[z]·B[z]^T ----------
// m97 structure, 128x128 tile, BK=64, global_load_lds, XOR-swizzled LDS.
// grid.x = (M/BM)*(N/BN) with GM=8 grouped-supertile mapping; grid.z = batch.
#define BM 128
#define BN 128
#define BK 64
#define GM 8

__global__ __launch_bounds__(256) void gemm_f16(const half_t* __restrict__ A,
                                                const half_t* __restrict__ B,
                                                float* __restrict__ C, int M, int N, int K,
                                                size_t sA, size_t sB, size_t sC) {
  __shared__ __align__(16) half_t As[BM * BK];
  __shared__ __align__(16) half_t Bs[BN * BK];
  const int tid = threadIdx.x;
  const int nbn = N / BN;
  // grouped-supertile decode: groups of GM bm-rows sweep all bn
  const int lin = blockIdx.x;
  const int per_group = GM * nbn;
  const int g = lin / per_group, r = lin % per_group;
  const int bm = g * GM + (r % GM);
  const int bn = r / GM;
  const int wave = tid >> 6, lane = tid & 63;
  const int wm = (wave & 1) * 64, wn = (wave >> 1) * 64;
  const int mrow = lane & 15, quad = lane >> 4;

  f32x4 acc[4][4];
#pragma unroll
  for (int i = 0; i < 4; i++)
#pragma unroll
    for (int j = 0; j < 4; j++) acc[i][j] = {0.f, 0.f, 0.f, 0.f};

  const half_t* Ag = A + (size_t)blockIdx.z * sA + (size_t)(bm * BM) * K;
  const half_t* Bg = B + (size_t)blockIdx.z * sB + (size_t)(bn * BN) * K;

  for (int k0 = 0; k0 < K; k0 += BK) {
#pragma unroll
    for (int i = 0; i < 4; i++) {
      int cid = i * 256 + tid;
      int row = cid >> 3, slot = cid & 7;
      int chunk = slot ^ (row & 7);
      gload16(Ag + (size_t)row * K + k0 + chunk * 8, &As[row * BK + slot * 8]);
      gload16(Bg + (size_t)row * K + k0 + chunk * 8, &Bs[row * BK + slot * 8]);
    }
    __builtin_amdgcn_s_waitcnt(0);
    __syncthreads();
#pragma unroll
    for (int ks = 0; ks < 2; ks++) {
      f16x8 af[4], bf[4];
#pragma unroll
      for (int i = 0; i < 4; i++) {
        int ra = wm + i * 16 + mrow;
        int rb = wn + i * 16 + mrow;
        int sa = (ks * 4 + quad) ^ (ra & 7);
        int sb = (ks * 4 + quad) ^ (rb & 7);
        af[i] = *(const f16x8*)(&As[ra * BK + sa * 8]);
        bf[i] = *(const f16x8*)(&Bs[rb * BK + sb * 8]);
      }
#pragma unroll
      for (int mi = 0; mi < 4; mi++)
#pragma unroll
        for (int ni = 0; ni < 4; ni++)
          acc[mi][ni] =
              __builtin_amdgcn_mfma_f32_16x16x32_f16(af[mi], bf[ni], acc[mi][ni], 0, 0, 0);
    }
    __syncthreads();
  }
  // epilogue: D[row=(quad*4+r)][col=lane&15] per 16x16 tile [m89/m91]
  float* Cb = C + (size_t)blockIdx.z * sC;
#pragma unroll
  for (int mi = 0; mi < 4; mi++) {
#pragma unroll
    for (int ni = 0; ni < 4; ni++) {
      int row0 = bm * BM + wm + mi * 16 + quad * 4;
      int col = bn * BN + wn + ni * 16 + mrow;
      float* Cp = Cb + (size_t)row0 * N + col;
#pragma unroll
      for (int r2 = 0; r2 < 4; r2++) Cp[(size_t)r2 * N] = acc[mi][ni][r2];
    }
  }
}

// ---------------- row softmax (batched): S fp32 -> P fp16 ----------------
__global__ __launch_bounds__(256) void softmax_rows(const float* __restrict__ S,
                                                    half_t* __restrict__ P) {
  const size_t rbase = ((size_t)blockIdx.y * SEQ + blockIdx.x) * SEQ;
  const float4* Sr = (const float4*)(S + rbase);
  const int tid = threadIdx.x, lane = tid & 63, wave = tid >> 6;
  __shared__ float red[4];
  __shared__ float bc;
  float4 v[4];
  float m = -1e30f;
#pragma unroll
  for (int j = 0; j < 4; j++) {
    v[j] = Sr[tid + j * 256];
    m = fmaxf(m, fmaxf(fmaxf(v[j].x, v[j].y), fmaxf(v[j].z, v[j].w)));
  }
#pragma unroll
  for (int o = 32; o; o >>= 1) m = fmaxf(m, __shfl_xor(m, o));
  if (lane == 0) red[wave] = m;
  __syncthreads();
  if (tid == 0) bc = fmaxf(fmaxf(red[0], red[1]), fmaxf(red[2], red[3]));
  __syncthreads();
  m = bc;
  float s = 0.f;
#pragma unroll
  for (int j = 0; j < 4; j++) {
    v[j].x = __expf(v[j].x - m);
    v[j].y = __expf(v[j].y - m);
    v[j].z = __expf(v[j].z - m);
    v[j].w = __expf(v[j].w - m);
    s += v[j].x + v[j].y + v[j].z + v[j].w;
  }
#pragma unroll
  for (int o = 32; o; o >>= 1) s += __shfl_xor(s, o);
  __syncthreads();
  if (lane == 0) red[wave] = s;
  __syncthreads();
  if (tid == 0) bc = red[0] + red[1] + red[2] + red[3];
  __syncthreads();
  float r = 1.0f / bc;
  f16x4* Pr = (f16x4*)(P + rbase);
#pragma unroll
  for (int j = 0; j < 4; j++) {
    f16x4 o = {(half_t)(v[j].x * r), (half_t)(v[j].y * r), (half_t)(v[j].z * r),
               (half_t)(v[j].w * r)};
    Pr[tid + j * 256] = o;
  }
}

// ---------------- naive fp32 fallback ----------------
__global__ __launch_bounds__(256) void naive_attn(const float* __restrict__ enc,
                                                  const float* __restrict__ dec,
                                                  float* __restrict__ out) {
  const int b = blockIdx.y, t = blockIdx.x;
  const float* encb = enc + (size_t)b * SEQ * DDIM;
  const float* q = dec + ((size_t)b * SEQ + t) * DDIM;
  __shared__ float qs[DDIM];
  __shared__ float sc[SEQ];
  __shared__ float red[4];
  __shared__ float bc;
  const int tid = threadIdx.x, lane = tid & 63, wave = tid >> 6;
  for (int i = tid; i < DDIM; i += 256) qs[i] = q[i];
  __syncthreads();
  for (int e = tid; e < SEQ; e += 256) {
    const float* er = encb + (size_t)e * DDIM;
    float s = 0.f;
    for (int d = 0; d < DDIM; d += 4) {
      float4 ev = *(const float4*)(er + d);
      s += ev.x * qs[d] + ev.y * qs[d + 1] + ev.z * qs[d + 2] + ev.w * qs[d + 3];
    }
    sc[e] = s;
  }
  __syncthreads();
  float m = -1e30f;
  for (int e = tid; e < SEQ; e += 256) m = fmaxf(m, sc[e]);
#pragma unroll
  for (int o = 32; o; o >>= 1) m = fmaxf(m, __shfl_xor(m, o));
  if (lane == 0) red[wave] = m;
  __syncthreads();
  if (tid == 0) bc = fmaxf(fmaxf(red[0], red[1]), fmaxf(red[2], red[3]));
  __syncthreads();
  m = bc;
  float s = 0.f;
  for (int e = tid; e < SEQ; e += 256) {
    float p = __expf(sc[e] - m);
    sc[e] = p;
    s += p;
  }
#pragma unroll
  for (int o = 32; o; o >>= 1) s += __shfl_xor(s, o);
  __syncthreads();
  if (lane == 0) red[wave] = s;
  __syncthreads();
  if (tid == 0) bc = red[0] + red[1] + red[2] + red[3];
  __syncthreads();
  const float rinv = 1.0f / bc;
  const int d0 = tid * 4;
  float4 acc = {0.f, 0.f, 0.f, 0.f};
  for (int e = 0; e < SEQ; e++) {
    float p = sc[e];
    float4 ev = *(const float4*)(encb + (size_t)e * DDIM + d0);
    acc.x += p * ev.x;
    acc.y += p * ev.y;
    acc.z += p * ev.z;
    acc.w += p * ev.w;
  }
  float4* o4 = (float4*)(out + ((size_t)b * SEQ + t) * DDIM + d0);
  float4 res = {acc.x * rinv, acc.y * rinv, acc.z * rinv, acc.w * rinv};
  *o4 = res;
}

extern "C" void kernel_launch(void* const* d_in, const int* in_sizes, int n_in, void* d_out,
                              int out_size, void* d_ws, size_t ws_size, hipStream_t stream) {
  const float* enc = (const float*)d_in[0];
  const float* dec = (const float*)d_in[1];
  float* out = (float*)d_out;

  const size_t EL = (size_t)SEQ * DDIM;            // 4M elems per batch
  const size_t SM = (size_t)SEQ * SEQ;             // 16M elems per batch
  const size_t SZ_S1 = SM * 4;                     // 64 MiB (one batch of S)
  const size_t SZ_SA = NBATCH * SZ_S1;             // 256 MiB (all batches)
  const size_t SZ_P1 = SM * 2;                     // 32 MiB
  const size_t SZ_PA = NBATCH * SZ_P1;             // 128 MiB
  const size_t SZ_H = NBATCH * EL * 2;             // 32 MiB each of decF/encF/encT
  const size_t NEED_A = SZ_SA + SZ_PA + 3 * SZ_H;  // 480 MiB
  const size_t NEED_B = SZ_S1 + SZ_PA + 3 * SZ_H;  // 288 MiB
  const size_t NEED_C = SZ_S1 + SZ_P1 + 3 * SZ_H;  // 192 MiB (proven available)

  const int GB1 = (SEQ / BM) * (SEQ / BN);   // 1024 blocks per batch, gemm1
  const int GB2 = (SEQ / BM) * (DDIM / BN);  // 256 blocks per batch, gemm2

  if (ws_size >= NEED_C) {
    // pick tier
    int tier = (ws_size >= NEED_A) ? 0 : (ws_size >= NEED_B) ? 1 : 2;
    const size_t s_sz = (tier == 0) ? SZ_SA : SZ_S1;
    const size_t p_sz = (tier <= 1) ? SZ_PA : SZ_P1;
    char* w = (char*)d_ws;
    float* S = (float*)w;
    half_t* P = (half_t*)(w + s_sz);
    half_t* decF = (half_t*)(w + s_sz + p_sz);
    half_t* encF = (half_t*)(w + s_sz + p_sz + SZ_H);
    half_t* encT = (half_t*)(w + s_sz + p_sz + 2 * SZ_H);

    const int nconv = (int)(NBATCH * EL / 4 / 256);
    conv_f16<<<nconv, 256, 0, stream>>>(dec, decF);
    conv_f16<<<nconv, 256, 0, stream>>>(enc, encF);
    transpose_f16<<<dim3(SEQ / 32, DDIM / 32, NBATCH), 256, 0, stream>>>(enc, encT);

    if (tier == 0) {
      // fully batched: 3 fat dispatches
      gemm_f16<<<dim3(GB1, 1, NBATCH), 256, 0, stream>>>(decF, encF, S, SEQ, SEQ, DDIM, EL, EL,
                                                         SM);
      softmax_rows<<<dim3(SEQ, NBATCH), 256, 0, stream>>>(S, P);
      gemm_f16<<<dim3(GB2, 1, NBATCH), 256, 0, stream>>>(P, encT, out, SEQ, DDIM, SEQ, SM, EL,
                                                         EL);
    } else if (tier == 1) {
      // per-batch gemm1+softmax (S reused), batched gemm2
      for (int b = 0; b < NBATCH; b++) {
        gemm_f16<<<dim3(GB1, 1, 1), 256, 0, stream>>>(decF + b * EL, encF + b * EL, S, SEQ, SEQ,
                                                      DDIM, 0, 0, 0);
        softmax_rows<<<dim3(SEQ, 1), 256, 0, stream>>>(S, P + b * SM);
      }
      gemm_f16<<<dim3(GB2, 1, NBATCH), 256, 0, stream>>>(P, encT, out, SEQ, DDIM, SEQ, SM, EL,
                                                         EL);
    } else {
      // round-3 schedule (all per-batch)
      for (int b = 0; b < NBATCH; b++) {
        gemm_f16<<<dim3(GB1, 1, 1), 256, 0, stream>>>(decF + b * EL, encF + b * EL, S, SEQ, SEQ,
                                                      DDIM, 0, 0, 0);
        softmax_rows<<<dim3(SEQ, 1), 256, 0, stream>>>(S, P);
        gemm_f16<<<dim3(GB2, 1, 1), 256, 0, stream>>>(P, encT + b * EL, out + b * EL, SEQ, DDIM,
                                                      SEQ, 0, 0, 0);
      }
    }
  } else {
    naive_attn<<<dim3(SEQ, NBATCH), 256, 0, stream>>>(enc, dec, out);
  }
}